// Round 6
// baseline (346.718 us; speedup 1.0000x reference)
//
#include <hip/hip_runtime.h>

#define TT   256    // timesteps
#define FF   23     // lab features
#define HH   100    // hidden
#define NROW 2      // batch rows per workgroup
#define NTHR 448    // 7 waves
#define NWG  512    // 1024 / NROW -> TWO wgs per CU (independent phases)

typedef unsigned int  u32;
typedef unsigned short u16;
typedef __attribute__((ext_vector_type(8))) short short8;  // 8 bf16 in 4 VGPRs
typedef __attribute__((ext_vector_type(4))) float f32x4;

__device__ __forceinline__ u16 f2bf(float f){           // RTNE f32->bf16
  u32 u = __float_as_uint(f);
  u += 0x7fffu + ((u >> 16) & 1u);
  return (u16)(u >> 16);
}
__device__ __forceinline__ float fsig(float x){
  return __builtin_amdgcn_rcpf(1.0f + __expf(-x));
}
__device__ __forceinline__ float ftanh(float x){
  return 1.0f - 2.0f * __builtin_amdgcn_rcpf(__expf(2.0f * x) + 1.0f);
}

// LDS layouts (bf16), NROW=2:
//  h/c: idx(b,k) = (k>>5)*64 + b*32 + ((k>>3)&3)*8 + (k&7)   [kf][b][q4][i]
//  x:   sXall[t*64 + b*32 + k]; k=24..27 carry the h[96..99] fold (written
//       each step by wave 6 lanes nl<4, q4<2)
// Batch row b sits at MFMA tile-row 4b (rows 0,4) -> C/D reg 0 of lanes
// q4=0,1 is real. A-frag reader lanes: nl in {0,4} (8 lanes/wave, 16B each).

__global__ __launch_bounds__(NTHR, 2) void tlstm7(
    const float* __restrict__ x_lab,  const float* __restrict__ t_lab,
    const float* __restrict__ x_state,const float* __restrict__ W_x,
    const float* __restrict__ W_h,    const float* __restrict__ b_lstm,
    const float* __restrict__ W_d,    const float* __restrict__ b_d,
    const float* __restrict__ W_state,const float* __restrict__ b_state,
    const float* __restrict__ W_fc,   const float* __restrict__ b_fc,
    float* __restrict__ out)
{
  __shared__ __align__(16) short sXall[TT * 64];  // 32 KB: x for ALL steps
  __shared__ __align__(16) short sHC[2][2][256];  // [buf][h=0/c=1][kf][b][q4][i]
  __shared__ __align__(16) float sDec[TT * NROW]; // [t*2 + b]
  __shared__ __align__(16) float sHF[NROW][128];  // fp32 h_final

  const int tid  = threadIdx.x;
  const int lane = tid & 63;
  const int w    = tid >> 6;        // wave 0..6
  const int nl   = lane & 15;
  const int q4   = lane >> 4;
  const int b0   = blockIdx.x * NROW;
  const int j    = w * 16 + nl;     // hidden column (j<=111; real <100)
  const bool jr  = (j < HH);

  // ---- zero h/c state buffers ----
  for (int i = tid; i < 512; i += NTHR) ((u32*)sHC)[i] = 0u;

  // ---- stage ENTIRE x sequence (bf16, frag layout, pads zeroed) ----
  for (int e = tid; e < TT * 64; e += NTHR) {
    int t = e >> 6, inner = e & 63, r = inner >> 5, f = inner & 31;
    float x = (f < FF) ? x_lab[((b0 + r)*TT + t)*FF + f] : 0.f;
    sXall[e] = (short)f2bf(x);
  }
  // ---- decay table ----
  for (int e = tid; e < TT * NROW; e += NTHR) {
    int t = e >> 1, r = e & 1;
    sDec[e] = 1.0f / logf(2.718281828459045f + t_lab[(b0 + r)*TT + t]);
  }

  // ---- persistent weight fragments (B-operand: col=nl -> j, k=kf*32+q4*8+i) ----
  short8 wh[4][3], wd[4], wx[4];
#pragma unroll
  for (int g = 0; g < 4; ++g)
#pragma unroll
    for (int kf = 0; kf < 3; ++kf) {
      short8 v;
#pragma unroll
      for (int i = 0; i < 8; ++i) {
        int k = kf*32 + q4*8 + i;                 // k <= 95: always real
        v[i] = (short)(jr ? f2bf(W_h[k*400 + g*HH + j]) : 0);
      }
      wh[g][kf] = v;
    }
#pragma unroll
  for (int kf = 0; kf < 4; ++kf) {
    short8 v;
#pragma unroll
    for (int i = 0; i < 8; ++i) {
      int k = kf*32 + q4*8 + i;
      v[i] = (short)((k < HH && jr) ? f2bf(W_d[k*HH + j]) : 0);
    }
    wd[kf] = v;
  }
#pragma unroll
  for (int g = 0; g < 4; ++g) {
    short8 v;
#pragma unroll
    for (int i = 0; i < 8; ++i) {
      int k = q4*8 + i;
      float x = 0.f;
      if (jr) {
        if (k < FF)                 x = W_x[k*400 + g*HH + j];
        else if (k >= 24 && k < 28) x = W_h[(96 + (k-24))*400 + g*HH + j]; // h-fold
      }
      v[i] = (short)f2bf(x);
    }
    wx[g] = v;
  }

  float bl[4], bd;
#pragma unroll
  for (int g = 0; g < 4; ++g) bl[g] = jr ? b_lstm[g*HH + j] : 0.f;
  bd = jr ? b_d[j] : 0.f;

  __syncthreads();

  const bool rdr  = (nl == 0) || (nl == 4);   // A-frag reader lanes (rows 0,4)
  const int rbase = (nl >> 2)*32 + q4*8;      // b*32 + q4*8 within 64-short frag
  const bool wr   = (q4 < 2);                 // pointwise-output lanes (b=q4)
  const int widx  = (j >> 5)*64 + q4*32 + ((j >> 3) & 3)*8 + (j & 7);

  short8 ha[3] = {}, ca[4] = {}, xa = {};     // stay 0 in non-reader lanes
  float cm = 0.f;                              // fp32 master cell (b=q4, col j)
  float hl = 0.f;

  const f32x4 zv = {0.f, 0.f, 0.f, 0.f};

  for (int t = 0; t < TT; ++t) {
    const short* hb = sHC[t & 1][0];
    const short* cb = sHC[t & 1][1];
    if (rdr) {
      xa = *(const short8*)(sXall + t*64 + rbase);
#pragma unroll
      for (int kf = 0; kf < 4; ++kf) ca[kf] = *(const short8*)(cb + kf*64 + rbase);
#pragma unroll
      for (int kf = 0; kf < 3; ++kf) ha[kf] = *(const short8*)(hb + kf*64 + rbase);
    }
    float dec = sDec[t*2 + (q4 & 1)];

    // gates: x-part first (independent of h/c reads), then treed h-chain
    f32x4 a0[4], a1[4];
#pragma unroll
    for (int g = 0; g < 4; ++g) {
      f32x4 b = {bl[g], bl[g], bl[g], bl[g]};
      a0[g] = __builtin_amdgcn_mfma_f32_16x16x32_bf16(xa, wx[g], b, 0, 0, 0);
    }
    // c @ W_d as two 2-deep chains
    f32x4 d0 = {bd, bd, bd, bd}, d1 = zv;
    d0 = __builtin_amdgcn_mfma_f32_16x16x32_bf16(ca[0], wd[0], d0, 0, 0, 0);
    d1 = __builtin_amdgcn_mfma_f32_16x16x32_bf16(ca[1], wd[1], d1, 0, 0, 0);
    d0 = __builtin_amdgcn_mfma_f32_16x16x32_bf16(ca[2], wd[2], d0, 0, 0, 0);
    d1 = __builtin_amdgcn_mfma_f32_16x16x32_bf16(ca[3], wd[3], d1, 0, 0, 0);
#pragma unroll
    for (int g = 0; g < 4; ++g) {
      a1[g] = __builtin_amdgcn_mfma_f32_16x16x32_bf16(ha[0], wh[g][0], zv,    0, 0, 0);
      a0[g] = __builtin_amdgcn_mfma_f32_16x16x32_bf16(ha[1], wh[g][1], a0[g], 0, 0, 0);
      a1[g] = __builtin_amdgcn_mfma_f32_16x16x32_bf16(ha[2], wh[g][2], a1[g], 0, 0, 0);
    }

    // ---- pointwise (C/D reg 0 = batch row q4, valid for q4<2) ----
    float cs   = ftanh(d0[0] + d1[0]);
    float cadj = cm - cs + cs*dec;
    float ig = fsig (a0[0][0] + a1[0][0]);
    float fg = fsig (a0[1][0] + a1[1][0]);
    float gg = ftanh(a0[2][0] + a1[2][0]);
    float og = fsig (a0[3][0] + a1[3][0]);
    float cnv = fg*cadj + ig*gg;
    cm = cnv;
    float hv = og*ftanh(cnv);
    hl = hv;

    short* hn = sHC[(t + 1) & 1][0];
    short* cn = sHC[(t + 1) & 1][1];
    if (wr) {
      hn[widx] = (short)f2bf(hv);
      cn[widx] = (short)f2bf(cnv);
      if (w == 6 && nl < 4 && t + 1 < TT)      // h[96..99] -> x-frag k=24..27
        sXall[(t + 1)*64 + q4*32 + 24 + nl] = (short)f2bf(hv);
    }

    __syncthreads();
  }

  // ---- epilogue ----
  if (wr) sHF[q4][j] = hl;
  __syncthreads();

  if (tid < NROW) {
    const int bg = b0 + tid;
    float y0 = b_fc[0], y1 = b_fc[1];
    for (int k = 0; k < HH; ++k) {
      float hv = sHF[tid][k];
      y0 += hv * W_fc[2*k];
      y1 += hv * W_fc[2*k + 1];
    }
#pragma unroll
    for (int k = 0; k < 20; ++k) {
      float a = b_state[k];
#pragma unroll
      for (int s = 0; s < 6; ++s) a += x_state[bg*6 + s] * W_state[s*20 + k];
      y0 += a * W_fc[2*(HH + k)];
      y1 += a * W_fc[2*(HH + k) + 1];
    }
    float m = fmaxf(y0, y1);
    float e0 = __expf(y0 - m), e1 = __expf(y1 - m);
    float inv = 1.0f / (e0 + e1);
    out[bg*2 + 0] = e0 * inv;
    out[bg*2 + 1] = e1 * inv;
  }
}

extern "C" void kernel_launch(void* const* d_in, const int* in_sizes, int n_in,
                              void* d_out, int out_size, void* d_ws, size_t ws_size,
                              hipStream_t stream) {
  const float* x_lab   = (const float*)d_in[0];
  const float* t_lab   = (const float*)d_in[1];
  const float* x_state = (const float*)d_in[2];
  const float* W_x     = (const float*)d_in[3];
  const float* W_h     = (const float*)d_in[4];
  const float* b_lstm  = (const float*)d_in[5];
  const float* W_d     = (const float*)d_in[6];
  const float* b_d     = (const float*)d_in[7];
  const float* W_state = (const float*)d_in[8];
  const float* b_state = (const float*)d_in[9];
  const float* W_fc    = (const float*)d_in[10];
  const float* b_fc    = (const float*)d_in[11];
  float* outp = (float*)d_out;

  hipLaunchKernelGGL(tlstm7, dim3(NWG), dim3(NTHR), 0, stream,
                     x_lab, t_lab, x_state, W_x, W_h, b_lstm, W_d, b_d,
                     W_state, b_state, W_fc, b_fc, outp);
}

// Round 7
// 326.229 us; speedup vs baseline: 1.0628x; 1.0628x over previous
//
#include <hip/hip_runtime.h>

#define TT   256    // timesteps
#define FF   23     // lab features
#define HH   100    // hidden
#define NTHR 448    // 7 waves
#define NWG  256    // 4 rows per wg -> one wg per CU

typedef unsigned int  u32;
typedef unsigned short u16;
typedef __attribute__((ext_vector_type(8))) short short8;  // 8 bf16 in 4 VGPRs
typedef __attribute__((ext_vector_type(4))) float f32x4;

__device__ __forceinline__ u16 f2bf(float f){           // RTNE f32->bf16
  u32 u = __float_as_uint(f);
  u += 0x7fffu + ((u >> 16) & 1u);
  return (u16)(u >> 16);
}
__device__ __forceinline__ float fsig(float x){
  return __builtin_amdgcn_rcpf(1.0f + __expf(-x));
}
__device__ __forceinline__ float ftanh(float x){
  return 1.0f - 2.0f * __builtin_amdgcn_rcpf(__expf(2.0f * x) + 1.0f);
}

// Two staggered batch-sets per wg: set A = rows {b0,b0+1}, set B = {b0+2,b0+3}.
// Per barrier interval: ds_read one set's fragments, MFMA+pointwise the OTHER
// set from registers -> LDS latency/issue overlaps MFMA+VALU inside each wave.
//
// LDS layouts (bf16):
//  x-frag:  sX[set][t][r*32+k], k: 0-22 = x features, 23-26 = h[96..99] fold,
//           27-30 = c[96..99] fold, 31 = 1.0 (bias lane; biases live in the
//           weight frags at k31 -> no accumulator init movs).
//  h/c:     sH/sC[set][buf][(k>>5)*64 + r*32 + ((k>>3)&3)*8 + (k&7)], k<96.
// Set rows sit at MFMA tile rows 0,4 -> C/D reg 0 of lanes q4<2 is real.
// A-frag reader lanes: nl in {0,4} (8 lanes, 128B contiguous, conflict-free).

__global__ __launch_bounds__(NTHR, 2) void tlstm8(
    const float* __restrict__ x_lab,  const float* __restrict__ t_lab,
    const float* __restrict__ x_state,const float* __restrict__ W_x,
    const float* __restrict__ W_h,    const float* __restrict__ b_lstm,
    const float* __restrict__ W_d,    const float* __restrict__ b_d,
    const float* __restrict__ W_state,const float* __restrict__ b_state,
    const float* __restrict__ W_fc,   const float* __restrict__ b_fc,
    float* __restrict__ out)
{
  __shared__ __align__(16) short sX[2][TT][64];   // 64 KB
  __shared__ __align__(16) short sH[2][2][192];   // [set][buf][..] k<96
  __shared__ __align__(16) short sC[2][2][192];
  __shared__ __align__(16) float sDec[TT][4];     // [t][global row]
  __shared__ __align__(16) float sHF[4][128];     // fp32 h_final

  const int tid  = threadIdx.x;
  const int lane = tid & 63;
  const int w    = tid >> 6;        // wave 0..6
  const int nl   = lane & 15;
  const int q4   = lane >> 4;
  const int b0   = blockIdx.x * 4;
  const int j    = w * 16 + nl;     // hidden column (j<=111; real <100)
  const bool jr  = (j < HH);

  // ---- zero h/c buffers (t=0 state) ----
  for (int i = tid; i < 2*2*192; i += NTHR) { ((short*)sH)[i] = 0; ((short*)sC)[i] = 0; }

  // ---- stage x for BOTH sets, all t (features + zeroed folds + 1.0 at k31) ----
  for (int e = tid; e < 2*TT*64; e += NTHR) {
    int s = e >> 14, t = (e >> 6) & (TT-1), inner = e & 63, r = inner >> 5, k = inner & 31;
    float v = 0.f;
    if (k < FF)       v = x_lab[((b0 + s*2 + r)*TT + t)*FF + k];
    else if (k == 31) v = 1.0f;
    sX[s][t][inner] = (short)f2bf(v);
  }
  // ---- decay table ----
  for (int e = tid; e < TT*4; e += NTHR) {
    int t = e >> 2, r = e & 3;
    sDec[t][r] = 1.0f / logf(2.718281828459045f + t_lab[(b0 + r)*TT + t]);
  }

  // ---- persistent weight fragments (B-operand: col=nl -> j, k=q4*8+i) ----
  short8 wh[4][3], wd[4], wx[4];
#pragma unroll
  for (int g = 0; g < 4; ++g)
#pragma unroll
    for (int kf = 0; kf < 3; ++kf) {
      short8 v;
#pragma unroll
      for (int i = 0; i < 8; ++i) {
        int k = kf*32 + q4*8 + i;                 // k <= 95: always real
        v[i] = (short)(jr ? f2bf(W_h[k*400 + g*HH + j]) : 0);
      }
      wh[g][kf] = v;
    }
#pragma unroll
  for (int kf = 0; kf < 3; ++kf) {
    short8 v;
#pragma unroll
    for (int i = 0; i < 8; ++i) {
      int k = kf*32 + q4*8 + i;
      v[i] = (short)(jr ? f2bf(W_d[k*HH + j]) : 0);
    }
    wd[kf] = v;
  }
  { // x-frag-matched d-weights: c-fold rows + b_d at k31
    short8 v;
#pragma unroll
    for (int i = 0; i < 8; ++i) {
      int k = q4*8 + i;
      float x = 0.f;
      if (jr) {
        if (k >= 27 && k < 31) x = W_d[(96 + (k-27))*HH + j];
        else if (k == 31)      x = b_d[j];
      }
      v[i] = (short)f2bf(x);
    }
    wd[3] = v;
  }
#pragma unroll
  for (int g = 0; g < 4; ++g) { // x-weights: features + h-fold rows + bias at k31
    short8 v;
#pragma unroll
    for (int i = 0; i < 8; ++i) {
      int k = q4*8 + i;
      float x = 0.f;
      if (jr) {
        if (k < FF)                 x = W_x[k*400 + g*HH + j];
        else if (k >= 23 && k < 27) x = W_h[(96 + (k-23))*400 + g*HH + j];
        else if (k == 31)           x = b_lstm[g*HH + j];
      }
      v[i] = (short)f2bf(x);
    }
    wx[g] = v;
  }

  __syncthreads();

  const bool rdr   = (nl == 0) || (nl == 4);   // A-frag reader lanes
  const int  rbase = (nl >> 2)*32 + q4*8;
  const int  widx  = (j >> 5)*64 + q4*32 + ((j >> 3) & 3)*8 + (j & 7); // k=j<96
  const bool wbuf  = (j < 96);
  const bool wfold = (w == 6) && (nl < 4);     // j in 96..99

  short8 xA={},cA0={},cA1={},cA2={},hA0={},hA1={},hA2={};
  short8 xB={},cB0={},cB1={},cB2={},hB0={},hB1={},hB2={};
  float cmA=0.f, cmB=0.f, hlA=0.f, hlB=0.f;
  const f32x4 zv = {0.f, 0.f, 0.f, 0.f};

#define MFMA16(a,b,c) __builtin_amdgcn_mfma_f32_16x16x32_bf16(a, b, c, 0, 0, 0)

  // ---- prologue: read A(0) ----
  if (rdr) {
    xA  = *(const short8*)(sX[0][0] + rbase);
    cA0 = *(const short8*)(sC[0][0] +       rbase);
    cA1 = *(const short8*)(sC[0][0] +  64 + rbase);
    cA2 = *(const short8*)(sC[0][0] + 128 + rbase);
    hA0 = *(const short8*)(sH[0][0] +       rbase);
    hA1 = *(const short8*)(sH[0][0] +  64 + rbase);
    hA2 = *(const short8*)(sH[0][0] + 128 + rbase);
  }

  for (int t = 0; t < TT; ++t) {
    const int pc = t & 1, pn = pc ^ 1;

    // ======== interval X: read B(t) ; compute A(t) -> A(t+1) ========
    if (rdr) {
      xB  = *(const short8*)(sX[1][t] + rbase);
      cB0 = *(const short8*)(sC[1][pc] +       rbase);
      cB1 = *(const short8*)(sC[1][pc] +  64 + rbase);
      cB2 = *(const short8*)(sC[1][pc] + 128 + rbase);
      hB0 = *(const short8*)(sH[1][pc] +       rbase);
      hB1 = *(const short8*)(sH[1][pc] +  64 + rbase);
      hB2 = *(const short8*)(sH[1][pc] + 128 + rbase);
    }
    {
      f32x4 d = MFMA16(cA0, wd[0], zv);
      d = MFMA16(cA1, wd[1], d); d = MFMA16(cA2, wd[2], d); d = MFMA16(xA, wd[3], d);
      f32x4 a0 = MFMA16(xA, wx[0], zv), a1 = MFMA16(xA, wx[1], zv);
      f32x4 a2 = MFMA16(xA, wx[2], zv), a3 = MFMA16(xA, wx[3], zv);
      a0 = MFMA16(hA0, wh[0][0], a0); a1 = MFMA16(hA0, wh[1][0], a1);
      a2 = MFMA16(hA0, wh[2][0], a2); a3 = MFMA16(hA0, wh[3][0], a3);
      a0 = MFMA16(hA1, wh[0][1], a0); a1 = MFMA16(hA1, wh[1][1], a1);
      a2 = MFMA16(hA1, wh[2][1], a2); a3 = MFMA16(hA1, wh[3][1], a3);
      a0 = MFMA16(hA2, wh[0][2], a0); a1 = MFMA16(hA2, wh[1][2], a1);
      a2 = MFMA16(hA2, wh[2][2], a2); a3 = MFMA16(hA2, wh[3][2], a3);

      float dec  = sDec[t][q4 & 1];
      float cs   = ftanh(d[0]);
      float cadj = cmA - cs + cs*dec;
      float ig = fsig(a0[0]), fg = fsig(a1[0]), gg = ftanh(a2[0]), og = fsig(a3[0]);
      float cnv = fg*cadj + ig*gg;  cmA = cnv;
      float hv  = og*ftanh(cnv);    hlA = hv;
      if (q4 < 2) {
        if (wbuf) {
          sH[0][pn][widx] = (short)f2bf(hv);
          sC[0][pn][widx] = (short)f2bf(cnv);
        } else if (wfold && t + 1 < TT) {
          sX[0][t+1][q4*32 + 23 + nl] = (short)f2bf(hv);
          sX[0][t+1][q4*32 + 27 + nl] = (short)f2bf(cnv);
        }
      }
    }
    __syncthreads();

    // ======== interval Y: read A(t+1) ; compute B(t) -> B(t+1) ========
    if (rdr && t + 1 < TT) {
      xA  = *(const short8*)(sX[0][t+1] + rbase);
      cA0 = *(const short8*)(sC[0][pn] +       rbase);
      cA1 = *(const short8*)(sC[0][pn] +  64 + rbase);
      cA2 = *(const short8*)(sC[0][pn] + 128 + rbase);
      hA0 = *(const short8*)(sH[0][pn] +       rbase);
      hA1 = *(const short8*)(sH[0][pn] +  64 + rbase);
      hA2 = *(const short8*)(sH[0][pn] + 128 + rbase);
    }
    {
      f32x4 d = MFMA16(cB0, wd[0], zv);
      d = MFMA16(cB1, wd[1], d); d = MFMA16(cB2, wd[2], d); d = MFMA16(xB, wd[3], d);
      f32x4 a0 = MFMA16(xB, wx[0], zv), a1 = MFMA16(xB, wx[1], zv);
      f32x4 a2 = MFMA16(xB, wx[2], zv), a3 = MFMA16(xB, wx[3], zv);
      a0 = MFMA16(hB0, wh[0][0], a0); a1 = MFMA16(hB0, wh[1][0], a1);
      a2 = MFMA16(hB0, wh[2][0], a2); a3 = MFMA16(hB0, wh[3][0], a3);
      a0 = MFMA16(hB1, wh[0][1], a0); a1 = MFMA16(hB1, wh[1][1], a1);
      a2 = MFMA16(hB1, wh[2][1], a2); a3 = MFMA16(hB1, wh[3][1], a3);
      a0 = MFMA16(hB2, wh[0][2], a0); a1 = MFMA16(hB2, wh[1][2], a1);
      a2 = MFMA16(hB2, wh[2][2], a2); a3 = MFMA16(hB2, wh[3][2], a3);

      float dec  = sDec[t][2 + (q4 & 1)];
      float cs   = ftanh(d[0]);
      float cadj = cmB - cs + cs*dec;
      float ig = fsig(a0[0]), fg = fsig(a1[0]), gg = ftanh(a2[0]), og = fsig(a3[0]);
      float cnv = fg*cadj + ig*gg;  cmB = cnv;
      float hv  = og*ftanh(cnv);    hlB = hv;
      if (q4 < 2) {
        if (wbuf) {
          sH[1][pn][widx] = (short)f2bf(hv);
          sC[1][pn][widx] = (short)f2bf(cnv);
        } else if (wfold && t + 1 < TT) {
          sX[1][t+1][q4*32 + 23 + nl] = (short)f2bf(hv);
          sX[1][t+1][q4*32 + 27 + nl] = (short)f2bf(cnv);
        }
      }
    }
    __syncthreads();
  }
#undef MFMA16

  // ---- epilogue ----
  if (q4 < 2 && jr) { sHF[q4][j] = hlA; sHF[2 + q4][j] = hlB; }
  __syncthreads();

  if (tid < 4) {
    const int bg = b0 + tid;
    float y0 = b_fc[0], y1 = b_fc[1];
    for (int k = 0; k < HH; ++k) {
      float hv = sHF[tid][k];
      y0 += hv * W_fc[2*k];
      y1 += hv * W_fc[2*k + 1];
    }
#pragma unroll
    for (int k = 0; k < 20; ++k) {
      float a = b_state[k];
#pragma unroll
      for (int s = 0; s < 6; ++s) a += x_state[bg*6 + s] * W_state[s*20 + k];
      y0 += a * W_fc[2*(HH + k)];
      y1 += a * W_fc[2*(HH + k) + 1];
    }
    float m = fmaxf(y0, y1);
    float e0 = __expf(y0 - m), e1 = __expf(y1 - m);
    float inv = 1.0f / (e0 + e1);
    out[bg*2 + 0] = e0 * inv;
    out[bg*2 + 1] = e1 * inv;
  }
}

extern "C" void kernel_launch(void* const* d_in, const int* in_sizes, int n_in,
                              void* d_out, int out_size, void* d_ws, size_t ws_size,
                              hipStream_t stream) {
  const float* x_lab   = (const float*)d_in[0];
  const float* t_lab   = (const float*)d_in[1];
  const float* x_state = (const float*)d_in[2];
  const float* W_x     = (const float*)d_in[3];
  const float* W_h     = (const float*)d_in[4];
  const float* b_lstm  = (const float*)d_in[5];
  const float* W_d     = (const float*)d_in[6];
  const float* b_d     = (const float*)d_in[7];
  const float* W_state = (const float*)d_in[8];
  const float* b_state = (const float*)d_in[9];
  const float* W_fc    = (const float*)d_in[10];
  const float* b_fc    = (const float*)d_in[11];
  float* outp = (float*)d_out;

  hipLaunchKernelGGL(tlstm8, dim3(NWG), dim3(NTHR), 0, stream,
                     x_lab, t_lab, x_state, W_x, W_h, b_lstm, W_d, b_d,
                     W_state, b_state, W_fc, b_fc, outp);
}

// Round 8
// 209.737 us; speedup vs baseline: 1.6531x; 1.5554x over previous
//
#include <hip/hip_runtime.h>

#define TT   256    // timesteps
#define FF   23     // lab features
#define HH   100    // hidden
#define NTHR 448    // 7 waves
#define NWG  256    // 4 rows per wg -> one wg per CU

typedef unsigned int  u32;
typedef unsigned short u16;
typedef __attribute__((ext_vector_type(8))) short short8;  // 8 bf16 in 4 VGPRs
typedef __attribute__((ext_vector_type(4))) float f32x4;

__device__ __forceinline__ u16 f2bf(float f){           // RTNE f32->bf16
  u32 u = __float_as_uint(f);
  u += 0x7fffu + ((u >> 16) & 1u);
  return (u16)(u >> 16);
}
__device__ __forceinline__ float fsig(float x){
  return __builtin_amdgcn_rcpf(1.0f + __expf(-x));
}
__device__ __forceinline__ float ftanh(float x){
  return 1.0f - 2.0f * __builtin_amdgcn_rcpf(__expf(2.0f * x) + 1.0f);
}

// One wg/CU, 4 batch rows in ONE M=16 tile-set (rows at tile-rows 4b ->
// C/D reg 0 of lane (q4,nl) is row q4). 7 waves x 16 j-cols = 112 (real 100).
//
// LDS (bf16). A K=32 frag = 128 shorts laid [r][k]: addr = r*32 + k.
// Reader lane (q4, nl in {0,4,8,12}): 8 shorts at (nl>>2)*32 + q4*8
//   -> 16 lanes span 256B contiguous, conflict-free ds_read_b128.
//  sX[t]:   k 0-22 = x features, 23-26 = h[96..99] fold, 27-30 = c[96..99]
//           fold, 31 = 1.0 (biases live in weight frags at k31).
//  sHC[buf][h|c][kf][128]: k = kf*32 + (k&31), covers j<96 only.
// Per step per wave: 7 ds_read_b128, 20 MFMA in 10 independent 2-deep
// chains (d-chain first: it heads the serial pointwise dependency).

__global__ __launch_bounds__(NTHR, 2) void tlstm9(
    const float* __restrict__ x_lab,  const float* __restrict__ t_lab,
    const float* __restrict__ x_state,const float* __restrict__ W_x,
    const float* __restrict__ W_h,    const float* __restrict__ b_lstm,
    const float* __restrict__ W_d,    const float* __restrict__ b_d,
    const float* __restrict__ W_state,const float* __restrict__ b_state,
    const float* __restrict__ W_fc,   const float* __restrict__ b_fc,
    float* __restrict__ out)
{
  __shared__ __align__(16) u16  sX[TT][128];    // 64 KB
  __shared__ __align__(16) u16  sHC[2][2][384]; // [buf][h=0/c=1][kf*128 + r*32 + k]
  __shared__ __align__(16) float sDec[TT][4];
  __shared__ __align__(16) float sHF[4][128];

  const int tid  = threadIdx.x;
  const int lane = tid & 63;
  const int w    = tid >> 6;        // wave 0..6
  const int nl   = lane & 15;
  const int q4   = lane >> 4;
  const int b0   = blockIdx.x * 4;
  const int j    = w * 16 + nl;     // hidden column (<=111; real <100)
  const bool jr  = (j < HH);

  // ---- zero h/c buffers ----
  for (int i = tid; i < 2*2*384/2; i += NTHR) ((u32*)sHC)[i] = 0u;

  // ---- stage x frags for all t (features + zero folds + 1.0 at k31) ----
  for (int e = tid; e < TT*128; e += NTHR) {
    int t = e >> 7, inner = e & 127, r = inner >> 5, k = inner & 31;
    float v = 0.f;
    if (k < FF)       v = x_lab[((b0 + r)*TT + t)*FF + k];
    else if (k == 31) v = 1.0f;
    sX[t][inner] = f2bf(v);
  }
  // ---- decay table ----
  for (int e = tid; e < TT*4; e += NTHR) {
    int t = e >> 2, r = e & 3;
    sDec[t][r] = 1.0f / logf(2.718281828459045f + t_lab[(b0 + r)*TT + t]);
  }

  // ---- persistent weight fragments (B-operand: col=nl -> j, k=kf*32+q4*8+i) ----
  short8 wh[4][3], wd[3], wdx, wx[4];
#pragma unroll
  for (int g = 0; g < 4; ++g)
#pragma unroll
    for (int kf = 0; kf < 3; ++kf) {
      short8 v;
#pragma unroll
      for (int i = 0; i < 8; ++i) {
        int k = kf*32 + q4*8 + i;                 // k <= 95: always real
        v[i] = (short)(jr ? f2bf(W_h[k*400 + g*HH + j]) : 0);
      }
      wh[g][kf] = v;
    }
#pragma unroll
  for (int kf = 0; kf < 3; ++kf) {
    short8 v;
#pragma unroll
    for (int i = 0; i < 8; ++i) {
      int k = kf*32 + q4*8 + i;
      v[i] = (short)(jr ? f2bf(W_d[k*HH + j]) : 0);
    }
    wd[kf] = v;
  }
  { // x-frag-matched d-weights: c-fold rows 27-30 + b_d at k31
    short8 v;
#pragma unroll
    for (int i = 0; i < 8; ++i) {
      int k = q4*8 + i;
      float x = 0.f;
      if (jr) {
        if (k >= 27 && k < 31) x = W_d[(96 + (k-27))*HH + j];
        else if (k == 31)      x = b_d[j];
      }
      v[i] = (short)f2bf(x);
    }
    wdx = v;
  }
#pragma unroll
  for (int g = 0; g < 4; ++g) { // x-weights: features + h-fold 23-26 + bias k31
    short8 v;
#pragma unroll
    for (int i = 0; i < 8; ++i) {
      int k = q4*8 + i;
      float x = 0.f;
      if (jr) {
        if (k < FF)                 x = W_x[k*400 + g*HH + j];
        else if (k >= 23 && k < 27) x = W_h[(96 + (k-23))*400 + g*HH + j];
        else if (k == 31)           x = b_lstm[g*HH + j];
      }
      v[i] = (short)f2bf(x);
    }
    wx[g] = v;
  }

  __syncthreads();

  const bool rdr   = ((nl & 3) == 0);          // 16 reader lanes
  const int  rbase = (nl >> 2)*32 + q4*8;
  const int  widx  = (j >> 5)*128 + q4*32 + (j & 31);  // valid for j<96
  const bool wbuf  = (w < 6);
  const bool wfold = (w == 6) && (nl < 4);     // j in 96..99 -> x-frag fold

  float cm = 0.f, hl = 0.f;
  const f32x4 zv = {0.f, 0.f, 0.f, 0.f};

#define MFMA16(a,b,c) __builtin_amdgcn_mfma_f32_16x16x32_bf16(a, b, c, 0, 0, 0)

#define STEP_BODY(T, PC, PN)                                                  \
  {                                                                           \
    const u16* hb = sHC[PC][0];                                               \
    const u16* cb = sHC[PC][1];                                               \
    u16* hn = sHC[PN][0];                                                     \
    u16* cn = sHC[PN][1];                                                     \
    short8 xa={},ha0={},ha1={},ha2={},ca0={},ca1={},ca2={};                   \
    if (rdr) {                                                                \
      ca0 = *(const short8*)(cb +       rbase);                               \
      ca1 = *(const short8*)(cb + 128 + rbase);                               \
      ca2 = *(const short8*)(cb + 256 + rbase);                               \
      xa  = *(const short8*)(sX[T] + rbase);                                  \
      ha0 = *(const short8*)(hb +       rbase);                               \
      ha1 = *(const short8*)(hb + 128 + rbase);                               \
      ha2 = *(const short8*)(hb + 256 + rbase);                               \
    }                                                                         \
    float dec = sDec[T][q4];                                                  \
    /* d first (heads the pointwise chain), 2-deep chains */                  \
    f32x4 d0 = MFMA16(ca0, wd[0], zv), d1 = MFMA16(ca1, wd[1], zv);           \
    d0 = MFMA16(ca2, wd[2], d0);       d1 = MFMA16(xa, wdx, d1);              \
    f32x4 p0[4], p1[4];                                                       \
    _Pragma("unroll")                                                         \
    for (int g = 0; g < 4; ++g) {                                             \
      p0[g] = MFMA16(xa,  wx[g],    zv);                                      \
      p1[g] = MFMA16(ha0, wh[g][0], zv);                                      \
      p0[g] = MFMA16(ha1, wh[g][1], p0[g]);                                   \
      p1[g] = MFMA16(ha2, wh[g][2], p1[g]);                                   \
    }                                                                         \
    float cs   = ftanh(d0[0] + d1[0]);                                        \
    float cadj = cm - cs + cs*dec;                                            \
    float ig = fsig (p0[0][0] + p1[0][0]);                                    \
    float fg = fsig (p0[1][0] + p1[1][0]);                                    \
    float gg = ftanh(p0[2][0] + p1[2][0]);                                    \
    float og = fsig (p0[3][0] + p1[3][0]);                                    \
    float cnv = fg*cadj + ig*gg;  cm = cnv;                                   \
    float hv  = og*ftanh(cnv);    hl = hv;                                    \
    u32 pk;                                                                   \
    asm("v_cvt_pk_bf16_f32 %0, %1, %2" : "=v"(pk) : "v"(hv), "v"(cnv));       \
    if (wbuf) {                                                               \
      hn[widx] = (u16)pk;                                                     \
      cn[widx] = (u16)(pk >> 16);                                             \
    } else if (wfold && (T) + 1 < TT) {                                       \
      sX[(T)+1][q4*32 + 23 + nl] = (u16)pk;                                   \
      sX[(T)+1][q4*32 + 27 + nl] = (u16)(pk >> 16);                           \
    }                                                                         \
    __syncthreads();                                                          \
  }

  for (int t = 0; t < TT; t += 2) {
    STEP_BODY(t,     0, 1)
    STEP_BODY(t + 1, 1, 0)
  }
#undef STEP_BODY
#undef MFMA16

  // ---- epilogue ----
  if (jr) sHF[q4][j] = hl;
  __syncthreads();

  if (tid < 4) {
    const int bg = b0 + tid;
    float y0 = b_fc[0], y1 = b_fc[1];
    for (int k = 0; k < HH; ++k) {
      float hv = sHF[tid][k];
      y0 += hv * W_fc[2*k];
      y1 += hv * W_fc[2*k + 1];
    }
#pragma unroll
    for (int k = 0; k < 20; ++k) {
      float a = b_state[k];
#pragma unroll
      for (int s = 0; s < 6; ++s) a += x_state[bg*6 + s] * W_state[s*20 + k];
      y0 += a * W_fc[2*(HH + k)];
      y1 += a * W_fc[2*(HH + k) + 1];
    }
    float m = fmaxf(y0, y1);
    float e0 = __expf(y0 - m), e1 = __expf(y1 - m);
    float inv = 1.0f / (e0 + e1);
    out[bg*2 + 0] = e0 * inv;
    out[bg*2 + 1] = e1 * inv;
  }
}

extern "C" void kernel_launch(void* const* d_in, const int* in_sizes, int n_in,
                              void* d_out, int out_size, void* d_ws, size_t ws_size,
                              hipStream_t stream) {
  const float* x_lab   = (const float*)d_in[0];
  const float* t_lab   = (const float*)d_in[1];
  const float* x_state = (const float*)d_in[2];
  const float* W_x     = (const float*)d_in[3];
  const float* W_h     = (const float*)d_in[4];
  const float* b_lstm  = (const float*)d_in[5];
  const float* W_d     = (const float*)d_in[6];
  const float* b_d     = (const float*)d_in[7];
  const float* W_state = (const float*)d_in[8];
  const float* b_state = (const float*)d_in[9];
  const float* W_fc    = (const float*)d_in[10];
  const float* b_fc    = (const float*)d_in[11];
  float* outp = (float*)d_out;

  hipLaunchKernelGGL(tlstm9, dim3(NWG), dim3(NTHR), 0, stream,
                     x_lab, t_lab, x_state, W_x, W_h, b_lstm, W_d, b_d,
                     W_state, b_state, W_fc, b_fc, outp);
}

// Round 9
// 177.369 us; speedup vs baseline: 1.9548x; 1.1825x over previous
//
#include <hip/hip_runtime.h>

#define TT   256    // timesteps
#define FF   23     // lab features
#define HH   100    // hidden
#define NTHR 448    // 7 waves
#define NWG  256    // 4 rows per wg -> one wg per CU

typedef unsigned int  u32;
typedef unsigned short u16;
typedef __attribute__((ext_vector_type(8))) short short8;  // 8 bf16 in 4 VGPRs
typedef __attribute__((ext_vector_type(4))) float f32x4;

__device__ __forceinline__ u16 f2bf(float f){           // RTNE f32->bf16
  u32 u = __float_as_uint(f);
  u += 0x7fffu + ((u >> 16) & 1u);
  return (u16)(u >> 16);
}
__device__ __forceinline__ float fsig(float x){
  return __builtin_amdgcn_rcpf(1.0f + __expf(-x));
}
__device__ __forceinline__ float ftanh(float x){
  return 1.0f - 2.0f * __builtin_amdgcn_rcpf(__expf(2.0f * x) + 1.0f);
}

// One wg/CU, 4 batch rows in ONE M=16 tile-set (rows at tile-rows 4b ->
// C/D elem 0 of lane (q4,nl) = (batch row q4, col j)). 7 waves x 16 cols.
//
// A-frag reads are UNCONDITIONAL: lane (q4,nl) reads (nl>>2)*32 + q4*8 --
// lanes within an nl-group of 4 hit the same address (broadcast, free).
// Tile rows nl%4!=0 receive duplicated batch-row data -> garbage in C/D
// elems 1..3, which are never consumed. No exec-mask branch, no zeroing.
//
// LDS (bf16):
//  sX[t][r*32+k]: k 0-22 x features, 23-26 h[96..99] fold, 27-30 c[96..99]
//                 fold, 31 = 1.0 (biases sit in weight frags at k31).
//  sHC[buf][h|c][kf*128 + r*32 + k]: j<96 exactly (96 = 3 frags x 32).
// Issue order per step: xa read -> 5 xa-MFMAs (d1 + 4 gate-x) -> 3 ca-MFMAs
// (d done by #8) -> cs/cadj on VALU overlapping the 12 gate-h MFMAs.

__global__ __launch_bounds__(NTHR, 2) void tlstm10(
    const float* __restrict__ x_lab,  const float* __restrict__ t_lab,
    const float* __restrict__ x_state,const float* __restrict__ W_x,
    const float* __restrict__ W_h,    const float* __restrict__ b_lstm,
    const float* __restrict__ W_d,    const float* __restrict__ b_d,
    const float* __restrict__ W_state,const float* __restrict__ b_state,
    const float* __restrict__ W_fc,   const float* __restrict__ b_fc,
    float* __restrict__ out)
{
  __shared__ __align__(16) u16  sX[TT][128];    // 64 KB
  __shared__ __align__(16) u16  sHC[2][2][384]; // [buf][h=0/c=1][kf*128+r*32+k]
  __shared__ __align__(16) float sDec[TT][4];   // dec(t,r) - 1
  __shared__ __align__(16) float sHF[4][128];

  const int tid  = threadIdx.x;
  const int lane = tid & 63;
  const int w    = tid >> 6;        // wave 0..6
  const int nl   = lane & 15;
  const int q4   = lane >> 4;
  const int b0   = blockIdx.x * 4;
  const int j    = w * 16 + nl;     // hidden column (<=111; real <100)
  const bool jr  = (j < HH);

  // ---- zero h/c buffers ----
  for (int i = tid; i < 2*2*384/2; i += NTHR) ((u32*)sHC)[i] = 0u;

  // ---- stage x frags for all t (features + zero folds + 1.0 at k31) ----
  for (int e = tid; e < TT*128; e += NTHR) {
    int t = e >> 7, inner = e & 127, r = inner >> 5, k = inner & 31;
    float v = 0.f;
    if (k < FF)       v = x_lab[((b0 + r)*TT + t)*FF + k];
    else if (k == 31) v = 1.0f;
    sX[t][inner] = f2bf(v);
  }
  // ---- decay-minus-one table ----
  for (int e = tid; e < TT*4; e += NTHR) {
    int t = e >> 2, r = e & 3;
    sDec[t][r] = 1.0f / logf(2.718281828459045f + t_lab[(b0 + r)*TT + t]) - 1.0f;
  }

  // ---- persistent weight fragments (B-operand: col=nl -> j, k=kf*32+q4*8+i) ----
  short8 wh[4][3], wd[3], wdx, wx[4];
#pragma unroll
  for (int g = 0; g < 4; ++g)
#pragma unroll
    for (int kf = 0; kf < 3; ++kf) {
      short8 v;
#pragma unroll
      for (int i = 0; i < 8; ++i) {
        int k = kf*32 + q4*8 + i;                 // k <= 95: always real
        v[i] = (short)(jr ? f2bf(W_h[k*400 + g*HH + j]) : 0);
      }
      wh[g][kf] = v;
    }
#pragma unroll
  for (int kf = 0; kf < 3; ++kf) {
    short8 v;
#pragma unroll
    for (int i = 0; i < 8; ++i) {
      int k = kf*32 + q4*8 + i;
      v[i] = (short)(jr ? f2bf(W_d[k*HH + j]) : 0);
    }
    wd[kf] = v;
  }
  { // x-frag-matched d-weights: c-fold rows 27-30 + b_d at k31
    short8 v;
#pragma unroll
    for (int i = 0; i < 8; ++i) {
      int k = q4*8 + i;
      float x = 0.f;
      if (jr) {
        if (k >= 27 && k < 31) x = W_d[(96 + (k-27))*HH + j];
        else if (k == 31)      x = b_d[j];
      }
      v[i] = (short)f2bf(x);
    }
    wdx = v;
  }
#pragma unroll
  for (int g = 0; g < 4; ++g) { // x-weights: features + h-fold 23-26 + bias k31
    short8 v;
#pragma unroll
    for (int i = 0; i < 8; ++i) {
      int k = q4*8 + i;
      float x = 0.f;
      if (jr) {
        if (k < FF)                 x = W_x[k*400 + g*HH + j];
        else if (k >= 23 && k < 27) x = W_h[(96 + (k-23))*400 + g*HH + j];
        else if (k == 31)           x = b_lstm[g*HH + j];
      }
      v[i] = (short)f2bf(x);
    }
    wx[g] = v;
  }

  __syncthreads();

  const int  rbase = (nl >> 2)*32 + q4*8;      // broadcast within nl-groups
  const int  widx  = (j >> 5)*128 + q4*32 + (j & 31);  // valid for j<96
  const bool wbuf  = (w < 6);
  const bool wfold = (w == 6) && (nl < 4);     // j in 96..99 -> x-frag fold

  float cm = 0.f, hl = 0.f;
  const f32x4 zv = {0.f, 0.f, 0.f, 0.f};

#define MFMA16(a,b,c) __builtin_amdgcn_mfma_f32_16x16x32_bf16(a, b, c, 0, 0, 0)

#define STEP_BODY(T, PC, PN)                                                  \
  {                                                                           \
    const u16* hb = sHC[PC][0];                                               \
    const u16* cb = sHC[PC][1];                                               \
    u16* hn = sHC[PN][0];                                                     \
    u16* cn = sHC[PN][1];                                                     \
    /* reads in consumption order: xa first so its MFMAs start early */       \
    short8 xa  = *(const short8*)(sX[T] + rbase);                             \
    short8 ca0 = *(const short8*)(cb +       rbase);                          \
    short8 ca1 = *(const short8*)(cb + 128 + rbase);                          \
    short8 ca2 = *(const short8*)(cb + 256 + rbase);                          \
    short8 ha0 = *(const short8*)(hb +       rbase);                          \
    short8 ha1 = *(const short8*)(hb + 128 + rbase);                          \
    short8 ha2 = *(const short8*)(hb + 256 + rbase);                          \
    float decm1 = sDec[T][q4];                                                \
    /* 5 xa-MFMAs behind the first read only */                               \
    f32x4 d1 = MFMA16(xa, wdx,   zv);                                         \
    f32x4 p0 = MFMA16(xa, wx[0], zv);                                         \
    f32x4 p1 = MFMA16(xa, wx[1], zv);                                         \
    f32x4 p2 = MFMA16(xa, wx[2], zv);                                         \
    f32x4 p3 = MFMA16(xa, wx[3], zv);                                         \
    /* d completes by MFMA #8 -> its pointwise head overlaps the gates */     \
    f32x4 d0 = MFMA16(ca0, wd[0], zv);                                        \
    d1 = MFMA16(ca1, wd[1], d1);                                              \
    d0 = MFMA16(ca2, wd[2], d0);                                              \
    float csum = d0[0] + d1[0];                                               \
    float cs   = ftanh(csum);                                                 \
    float cadj = __builtin_fmaf(cs, decm1, cm);                               \
    /* 12 gate-h MFMAs; cs/cadj VALU work hides under their issue */          \
    p0 = MFMA16(ha0, wh[0][0], p0); p1 = MFMA16(ha0, wh[1][0], p1);           \
    p2 = MFMA16(ha0, wh[2][0], p2); p3 = MFMA16(ha0, wh[3][0], p3);           \
    p0 = MFMA16(ha1, wh[0][1], p0); p1 = MFMA16(ha1, wh[1][1], p1);           \
    p2 = MFMA16(ha1, wh[2][1], p2); p3 = MFMA16(ha1, wh[3][1], p3);           \
    p0 = MFMA16(ha2, wh[0][2], p0); p1 = MFMA16(ha2, wh[1][2], p1);           \
    p2 = MFMA16(ha2, wh[2][2], p2); p3 = MFMA16(ha2, wh[3][2], p3);           \
    float ig = fsig (p0[0]);                                                  \
    float fg = fsig (p1[0]);                                                  \
    float gg = ftanh(p2[0]);                                                  \
    float og = fsig (p3[0]);                                                  \
    float cnv = fg*cadj + ig*gg;  cm = cnv;                                   \
    float hv  = og*ftanh(cnv);    hl = hv;                                    \
    u32 pk;                                                                   \
    asm("v_cvt_pk_bf16_f32 %0, %1, %2" : "=v"(pk) : "v"(hv), "v"(cnv));       \
    if (wbuf) {                                                               \
      hn[widx] = (u16)pk;                                                     \
      cn[widx] = (u16)(pk >> 16);                                             \
    } else if (wfold && (T) + 1 < TT) {                                       \
      sX[(T)+1][q4*32 + 23 + nl] = (u16)pk;                                   \
      sX[(T)+1][q4*32 + 27 + nl] = (u16)(pk >> 16);                           \
    }                                                                         \
    __syncthreads();                                                          \
  }

  for (int t = 0; t < TT; t += 2) {
    STEP_BODY(t,     0, 1)
    STEP_BODY(t + 1, 1, 0)
  }
#undef STEP_BODY
#undef MFMA16

  // ---- epilogue ----
  if (jr) sHF[q4][j] = hl;
  __syncthreads();

  if (tid < 4) {
    const int bg = b0 + tid;
    float y0 = b_fc[0], y1 = b_fc[1];
    for (int k = 0; k < HH; ++k) {
      float hv = sHF[tid][k];
      y0 += hv * W_fc[2*k];
      y1 += hv * W_fc[2*k + 1];
    }
#pragma unroll
    for (int k = 0; k < 20; ++k) {
      float a = b_state[k];
#pragma unroll
      for (int s = 0; s < 6; ++s) a += x_state[bg*6 + s] * W_state[s*20 + k];
      y0 += a * W_fc[2*(HH + k)];
      y1 += a * W_fc[2*(HH + k) + 1];
    }
    float m = fmaxf(y0, y1);
    float e0 = __expf(y0 - m), e1 = __expf(y1 - m);
    float inv = 1.0f / (e0 + e1);
    out[bg*2 + 0] = e0 * inv;
    out[bg*2 + 1] = e1 * inv;
  }
}

extern "C" void kernel_launch(void* const* d_in, const int* in_sizes, int n_in,
                              void* d_out, int out_size, void* d_ws, size_t ws_size,
                              hipStream_t stream) {
  const float* x_lab   = (const float*)d_in[0];
  const float* t_lab   = (const float*)d_in[1];
  const float* x_state = (const float*)d_in[2];
  const float* W_x     = (const float*)d_in[3];
  const float* W_h     = (const float*)d_in[4];
  const float* b_lstm  = (const float*)d_in[5];
  const float* W_d     = (const float*)d_in[6];
  const float* b_d     = (const float*)d_in[7];
  const float* W_state = (const float*)d_in[8];
  const float* b_state = (const float*)d_in[9];
  const float* W_fc    = (const float*)d_in[10];
  const float* b_fc    = (const float*)d_in[11];
  float* outp = (float*)d_out;

  hipLaunchKernelGGL(tlstm10, dim3(NWG), dim3(NTHR), 0, stream,
                     x_lab, t_lab, x_state, W_x, W_h, b_lstm, W_d, b_d,
                     W_state, b_state, W_fc, b_fc, outp);
}